// Round 1
// baseline (358.185 us; speedup 1.0000x reference)
//
#include <hip/hip_runtime.h>
#include <hip/hip_bf16.h>

#define NN 4096
#define IC 128
#define OC 128
#define ED 16
#define EPB 128

// Phase 1: xw1b[n][c] = b1[c] + sum_k x[n][k] * W1[k][c]   (row-only part of layer 1)
__global__ __launch_bounds__(128) void k_xw1(
    const float* __restrict__ x, const float* __restrict__ W1,
    const float* __restrict__ b1, float* __restrict__ xw1b)
{
    __shared__ float xs[8][IC];
    const int t = threadIdx.x;
    const int r0 = blockIdx.x * 8;
    #pragma unroll
    for (int r = 0; r < 8; ++r) xs[r][t] = x[(size_t)(r0 + r) * IC + t];
    __syncthreads();
    float acc[8];
    const float bb = b1[t];
    #pragma unroll
    for (int r = 0; r < 8; ++r) acc[r] = bb;
    #pragma unroll 4
    for (int k = 0; k < IC; ++k) {
        const float w = W1[(size_t)k * OC + t];
        #pragma unroll
        for (int r = 0; r < 8; ++r) acc[r] = fmaf(xs[r][k], w, acc[r]);
    }
    #pragma unroll
    for (int r = 0; r < 8; ++r) xw1b[(size_t)(r0 + r) * OC + t] = acc[r];
}

// Phase 2: per-edge  h1 = relu(xw1b[row] + ea@W1e);  h2 = relu(h1@W2 + b2);
//          atomicAdd(out[col], h2)
// 128 threads = 2 waves per block; thread t owns output channel t:
//   - W2 column t (128 VGPR) and W1e column t (16 VGPR) in registers
//   - h1 broadcast through LDS (conflict-free broadcast float4 reads)
// Raw s_barrier + manual lgkmcnt(0) so depth-2 global prefetch (edge_attr,
// xw1b) stays in flight across the per-edge barrier (no vmcnt(0) drain).
__global__ __launch_bounds__(128, 2) void k_edge(
    const int* __restrict__ eidx, const float* __restrict__ eattr,
    const float* __restrict__ xw1b, const float* __restrict__ W1,
    const float* __restrict__ W2, const float* __restrict__ b2,
    float* __restrict__ out, int E)
{
    const int t = threadIdx.x;

    float w2c[128];
    #pragma unroll
    for (int k = 0; k < 128; ++k) w2c[k] = W2[(size_t)k * OC + t];
    float w1c[ED];
    #pragma unroll
    for (int d = 0; d < ED; ++d) w1c[d] = W1[(size_t)(IC + d) * OC + t];
    const float b2t = b2[t];

    __shared__ __align__(16) float hs[2][OC];
    __shared__ int srow[EPB];
    __shared__ int scol[EPB];

    const int e0 = blockIdx.x * EPB;
    const int nedge = min(EPB, E - e0);
    if (nedge <= 0) return;
    if (t < nedge) {
        srow[t] = eidx[e0 + t];
        scol[t] = eidx[E + e0 + t];
    }
    __syncthreads();

    float4 A0, A1, A2, A3, B0, B1, B2, B3;
    float Axw = 0.f, Bxw = 0.f;
    int Acol = 0, Bcol = 0;
    A0 = A1 = A2 = A3 = B0 = B1 = B2 = B3 = make_float4(0.f, 0.f, 0.f, 0.f);

    auto pref = [&](int i, float4& p0, float4& p1, float4& p2, float4& p3,
                    float& pxw, int& pcol) {
        const int r = srow[i];
        const int c = scol[i];
        const float4* p = (const float4*)(eattr + ((size_t)r * NN + c) * ED);
        p0 = p[0]; p1 = p[1]; p2 = p[2]; p3 = p[3];
        pxw = xw1b[(size_t)r * OC + t];
        pcol = c;
    };

    pref(0, A0, A1, A2, A3, Axw, Acol);
    if (nedge > 1) pref(1, B0, B1, B2, B3, Bxw, Bcol);

    int buf = 0;
    for (int i = 0; i < nedge; ++i) {
        const float4 a0 = A0, a1 = A1, a2 = A2, a3 = A3;
        const float xw = Axw;
        const int ccol = Acol;
        // rotate pipeline: B -> A, prefetch i+2 -> B
        A0 = B0; A1 = B1; A2 = B2; A3 = B3; Axw = Bxw; Acol = Bcol;
        if (i + 2 < nedge) pref(i + 2, B0, B1, B2, B3, Bxw, Bcol);

        // h1 for channel t
        float h = xw;
        h = fmaf(a0.x, w1c[0],  h); h = fmaf(a0.y, w1c[1],  h);
        h = fmaf(a0.z, w1c[2],  h); h = fmaf(a0.w, w1c[3],  h);
        h = fmaf(a1.x, w1c[4],  h); h = fmaf(a1.y, w1c[5],  h);
        h = fmaf(a1.z, w1c[6],  h); h = fmaf(a1.w, w1c[7],  h);
        h = fmaf(a2.x, w1c[8],  h); h = fmaf(a2.y, w1c[9],  h);
        h = fmaf(a2.z, w1c[10], h); h = fmaf(a2.w, w1c[11], h);
        h = fmaf(a3.x, w1c[12], h); h = fmaf(a3.y, w1c[13], h);
        h = fmaf(a3.z, w1c[14], h); h = fmaf(a3.w, w1c[15], h);
        h = fmaxf(h, 0.0f);

        hs[buf][t] = h;
        asm volatile("s_waitcnt lgkmcnt(0)" ::: "memory");
        __builtin_amdgcn_s_barrier();
        asm volatile("" ::: "memory");

        // h2[t] = relu(b2[t] + sum_k h1[k] * W2[k][t])
        float acc = b2t;
        const float4* hp = (const float4*)(&hs[buf][0]);
        #pragma unroll
        for (int k = 0; k < 32; ++k) {
            const float4 hv = hp[k];
            acc = fmaf(hv.x, w2c[4 * k + 0], acc);
            acc = fmaf(hv.y, w2c[4 * k + 1], acc);
            acc = fmaf(hv.z, w2c[4 * k + 2], acc);
            acc = fmaf(hv.w, w2c[4 * k + 3], acc);
        }
        acc = fmaxf(acc, 0.0f);

        atomicAdd(&out[(size_t)ccol * OC + t], acc);
        buf ^= 1;
    }
}

extern "C" void kernel_launch(void* const* d_in, const int* in_sizes, int n_in,
                              void* d_out, int out_size, void* d_ws, size_t ws_size,
                              hipStream_t stream) {
    const float* x    = (const float*)d_in[0];
    const int*   eidx = (const int*)d_in[1];
    const float* ea   = (const float*)d_in[2];
    const float* W1   = (const float*)d_in[3];
    const float* b1   = (const float*)d_in[4];
    const float* W2   = (const float*)d_in[5];
    const float* b2   = (const float*)d_in[6];
    float* out  = (float*)d_out;
    float* xw1b = (float*)d_ws;   // 4096*128*4 = 2 MB scratch

    const int E = in_sizes[1] / 2;

    hipMemsetAsync(d_out, 0, (size_t)out_size * sizeof(float), stream);
    k_xw1<<<NN / 8, 128, 0, stream>>>(x, W1, b1, xw1b);
    const int nblocks = (E + EPB - 1) / EPB;
    k_edge<<<nblocks, 128, 0, stream>>>(eidx, ea, xw1b, W1, W2, b2, out, E);
}